// Round 23
// baseline (100.061 us; speedup 1.0000x reference)
//
#include <hip/hip_runtime.h>
#include <hip/hip_bf16.h>
#include <cstdint>
#include <cstddef>

typedef __attribute__((ext_vector_type(8))) short short8;
typedef __attribute__((ext_vector_type(4))) short short4v;
typedef __attribute__((ext_vector_type(4))) float f32x4;
typedef __attribute__((ext_vector_type(16))) float f32x16;

#define HH 12
#define DD 64
#define NN 2048
#define CC 768
// 0.125 (HEAD_DIM^-0.5) * log2(e): lets attn use exp2 directly.
#define QSCALE 0.18033688011112042f
#define VKEY(r) ((((r) >> 1) ^ ((r) >> 3)) & 3)

#if defined(__has_builtin)
#if __has_builtin(__builtin_amdgcn_global_load_lds)
#define HAVE_GLOAD_LDS 1
#endif
#endif

#ifdef HAVE_GLOAD_LDS
// async global->LDS, 16B per lane; LDS dest is wave-uniform base + lane*16
#define GL16(gp, lp)                                                         \
  __builtin_amdgcn_global_load_lds(                                         \
      (__attribute__((address_space(1))) void*)(size_t)(const void*)(gp),   \
      (__attribute__((address_space(3))) void*)(lp), 16, 0, 0)
#endif

__device__ __forceinline__ float bf2f(short s) {
  union { uint32_t u; float f; } v;
  v.u = ((uint32_t)(uint16_t)s) << 16;
  return v.f;
}
__device__ __forceinline__ short f2bf(float f) {
  union { float f; uint32_t u; } v; v.f = f;
  uint32_t r = v.u + 0x7FFFu + ((v.u >> 16) & 1u);
  return (short)(r >> 16);
}
// packed f32x2 -> bf16x2 (low = a, high = b) in one instruction
__device__ __forceinline__ uint32_t cvtpk(float a, float b) {
  uint32_t r;
  asm("v_cvt_pk_bf16_f32 %0, %1, %2" : "=v"(r) : "v"(a), "v"(b));
  return r;
}
// raw hardware exp2 (1 instruction; avoids hipcc's non-fast-math denorm
// fixup sequence).  Confirmed R15: VALUBusy 55->34%.
__device__ __forceinline__ float exp2raw(float x) {
  float r;
  asm("v_exp_f32 %0, %1" : "=v"(r) : "v"(x));
  return r;
}

// ---------------------------------------------------------------------------
// Normalizer: fp32 -> bf16 for x, w_qkv, w_out.  Block 0 also zeroes cs
// (colsum accumulator, filled by gemm0's V^T epilogue atomics).
// ---------------------------------------------------------------------------
__global__ __launch_bounds__(256)
void norm_k(const float* __restrict__ s0, const float* __restrict__ s1,
            const float* __restrict__ s2,
            short* __restrict__ d0, short* __restrict__ d1,
            short* __restrict__ d2, float* __restrict__ cs)
{
  const int bid = blockIdx.x;
  if (bid == 0) {
#pragma unroll
    for (int i = 0; i < 6; ++i) cs[i * 256 + threadIdx.x] = 0.f;
  }
  const float* src; short* dst; int base;
  if (bid < 1536)      { src = s0; dst = d0; base = bid; }
  else if (bid < 2400) { src = s1; dst = d1; base = bid - 1536; }
  else                 { src = s2; dst = d2; base = bid - 2400; }
  const int idx = (base * 256 + (int)threadIdx.x) * 8;
  const float* sf = src + idx;
  f32x4 a = *(const f32x4*)sf;
  f32x4 b = *(const f32x4*)(sf + 4);
  short8 o;
  o[0] = f2bf(a[0]); o[1] = f2bf(a[1]); o[2] = f2bf(a[2]); o[3] = f2bf(a[3]);
  o[4] = f2bf(b[0]); o[5] = f2bf(b[1]); o[6] = f2bf(b[2]); o[7] = f2bf(b[3]);
  *(short8*)(dst + idx) = o;
}

// ---------------------------------------------------------------------------
// QKV GEMM (128x128), DOUBLE-BUFFERED async staging: one barrier per K-tile;
// STAGE(t+1) issued right after the barrier so its loads land during the
// compute of tile t (the barrier's implicit vmcnt-drain then retires a
// prefetch that had a full compute phase -- vs the old 2-barrier sync
// pattern where every tile paid exposed load latency).  LDS 64 KB.
// C[m,f] = sum_c A[m,c]*W[f,c] -> Q (x QSCALE), K, V^T; V^T epilogue also
// accumulates colsum cs via atomics (R21: -9.5 us).
// ---------------------------------------------------------------------------
__global__ __launch_bounds__(256, 2)
void gemm0_k(const short* __restrict__ A, const short* __restrict__ W,
             short* __restrict__ O0, short* __restrict__ O1,
             short* __restrict__ O2, float* __restrict__ cs)
{
  __shared__ __align__(16) short lA[2][128 * 64];
  __shared__ __align__(16) short lB[2][128 * 64];
  const int tid = threadIdx.x;
  const int w = tid >> 6, l = tid & 63;
  const int lq = l & 15, lh = l >> 4;
  const int m0 = blockIdx.y * 128;
  const int f0 = blockIdx.x * 128;

#ifdef HAVE_GLOAD_LDS
  const int lrow = l >> 3;                    // 0..7 within wave
  const int gseg = ((l & 7) ^ lrow) * 8;      // pre-swizzled element offset
#define G0STAGE(kb_, bo_)                                                    \
  do {                                                                       \
    _Pragma("unroll")                                                        \
    for (int j = 0; j < 4; ++j) {                                            \
      const int rw = j * 32 + w * 8;                                         \
      GL16(A + (size_t)(m0 + rw + lrow) * CC + (kb_) + gseg,                 \
           &lA[bo_][rw * 64]);                                               \
      GL16(W + (size_t)(f0 + rw + lrow) * CC + (kb_) + gseg,                 \
           &lB[bo_][rw * 64]);                                               \
    }                                                                        \
  } while (0)
#else
  const int seg = tid & 7;
  const int rbase = tid >> 3;
#define G0STAGE(kb_, bo_)                                                    \
  do {                                                                       \
    _Pragma("unroll")                                                        \
    for (int j = 0; j < 4; ++j) {                                            \
      const int row = j * 32 + rbase;                                        \
      const int dst = row * 128 + ((seg * 16) ^ ((row & 7) << 4));           \
      *(short8*)((char*)lA[bo_] + dst) =                                     \
          *(const short8*)(A + (size_t)(m0 + row) * CC + (kb_) + seg * 8);   \
      *(short8*)((char*)lB[bo_] + dst) =                                     \
          *(const short8*)(W + (size_t)(f0 + row) * CC + (kb_) + seg * 8);   \
    }                                                                        \
  } while (0)
#endif

  f32x4 acc[4][4] = {};

#ifdef HAVE_GLOAD_LDS
  G0STAGE(0, 0);
#endif
  for (int it = 0; it < CC / 64; ++it) {
    const int bo = it & 1;
#ifdef HAVE_GLOAD_LDS
    __syncthreads();                          // drains tile-it prefetch
    if (it + 1 < CC / 64) G0STAGE((it + 1) * 64, bo ^ 1);
#else
    __syncthreads();
    G0STAGE(it * 64, bo);
    __syncthreads();
#endif
    const int wr = (w >> 1) * 64, wc = (w & 1) * 64;
#pragma unroll
    for (int c = 0; c < 2; ++c) {
      short8 af[4], bfr[4];
#pragma unroll
      for (int i = 0; i < 4; ++i) {
        const int rowA = wr + i * 16 + lq;
        af[i] = *(const short8*)((char*)lA[bo] + rowA * 128 +
                                 ((c * 64 + lh * 16) ^ ((rowA & 7) << 4)));
        const int rowB = wc + i * 16 + lq;
        bfr[i] = *(const short8*)((char*)lB[bo] + rowB * 128 +
                                  ((c * 64 + lh * 16) ^ ((rowB & 7) << 4)));
      }
#pragma unroll
      for (int mi = 0; mi < 4; ++mi)
#pragma unroll
        for (int ni = 0; ni < 4; ++ni)
          acc[mi][ni] = __builtin_amdgcn_mfma_f32_16x16x32_bf16(
              af[mi], bfr[ni], acc[mi][ni], 0, 0, 0);
    }
  }

  const int wr = (w >> 1) * 64, wc = (w & 1) * 64;
#pragma unroll
  for (int ni = 0; ni < 4; ++ni) {
    const int fb = f0 + wc + ni * 16;
    const int which = fb / CC;          // uniform per fragment
    const int hd = fb - which * CC;
    const int h = hd >> 6;              // uniform
    const int d = (hd & 63) + lq;
    if (which == 0) {
#pragma unroll
      for (int mi = 0; mi < 4; ++mi) {
        const int mb = m0 + wr + mi * 16 + 4 * lh;
        const int b = mb >> 11;
        const int n = mb & 2047;
#pragma unroll
        for (int r = 0; r < 4; ++r)
          O0[(((size_t)(b * HH + h) * NN) + n + r) * DD + d] =
              f2bf(acc[mi][ni][r] * QSCALE);
      }
    } else if (which == 1) {
#pragma unroll
      for (int mi = 0; mi < 4; ++mi) {
        const int mb = m0 + wr + mi * 16 + 4 * lh;
        const int b = mb >> 11;
        const int n = mb & 2047;
#pragma unroll
        for (int r = 0; r < 4; ++r)
          O1[(((size_t)(b * HH + h) * NN) + n + r) * DD + d] =
              f2bf(acc[mi][ni][r]);
      }
    } else {
      float csp = 0.f;                  // this thread's colsum partial
#pragma unroll
      for (int mi = 0; mi < 4; ++mi) {
        const int mb = m0 + wr + mi * 16 + 4 * lh;
        const int b = mb >> 11;
        const int n = mb & 2047;
        short4v pk;
#pragma unroll
        for (int r = 0; r < 4; ++r) {
          pk[r] = f2bf(acc[mi][ni][r]);
          csp += acc[mi][ni][r];
        }
        *(short4v*)(O2 + ((size_t)(b * HH + h) * DD + d) * NN + n) = pk;
      }
      // lanes xor 16/32 differ only in lh (same d, different n-rows)
      csp += __shfl_xor(csp, 16);
      csp += __shfl_xor(csp, 32);
      if (lh == 0) {
        const int b = (m0 + wr) >> 11;  // wave-uniform (64-row span, no straddle)
        atomicAdd(&cs[(b * HH + h) * DD + d], csp);
      }
    }
  }
}

// ---------------------------------------------------------------------------
// Out-proj GEMM, 64x64 tiles (768 blocks = 3/CU), DOUBLE-BUFFERED async
// staging (same pattern as gemm0).  fp32 out + bias.  LDS 32 KB.
// ---------------------------------------------------------------------------
__global__ __launch_bounds__(256, 4)
void gemm1_k(const short* __restrict__ A, const short* __restrict__ W,
             const float* __restrict__ bias, float* __restrict__ Of)
{
  __shared__ __align__(16) short lA[2][64 * 64];
  __shared__ __align__(16) short lB[2][64 * 64];
  const int tid = threadIdx.x;
  const int w = tid >> 6, l = tid & 63;
  const int lq = l & 15, lh = l >> 4;
  const int m0 = blockIdx.y * 64;
  const int f0 = blockIdx.x * 64;

#ifdef HAVE_GLOAD_LDS
  const int lrow = l >> 3;
  const int gseg = ((l & 7) ^ lrow) * 8;
#define G1STAGE(kb_, bo_)                                                    \
  do {                                                                       \
    _Pragma("unroll")                                                        \
    for (int j = 0; j < 2; ++j) {                                            \
      const int rw = j * 32 + w * 8;                                         \
      GL16(A + (size_t)(m0 + rw + lrow) * CC + (kb_) + gseg,                 \
           &lA[bo_][rw * 64]);                                               \
      GL16(W + (size_t)(f0 + rw + lrow) * CC + (kb_) + gseg,                 \
           &lB[bo_][rw * 64]);                                               \
    }                                                                        \
  } while (0)
#else
  const int seg = tid & 7;
  const int rbase = tid >> 3;                 // 0..31
#define G1STAGE(kb_, bo_)                                                    \
  do {                                                                       \
    _Pragma("unroll")                                                        \
    for (int j = 0; j < 2; ++j) {                                            \
      const int row = j * 32 + rbase;                                        \
      const int dst = row * 128 + ((seg * 16) ^ ((row & 7) << 4));           \
      *(short8*)((char*)lA[bo_] + dst) =                                     \
          *(const short8*)(A + (size_t)(m0 + row) * CC + (kb_) + seg * 8);   \
      *(short8*)((char*)lB[bo_] + dst) =                                     \
          *(const short8*)(W + (size_t)(f0 + row) * CC + (kb_) + seg * 8);   \
    }                                                                        \
  } while (0)
#endif

  f32x4 acc[2][2] = {};

#ifdef HAVE_GLOAD_LDS
  G1STAGE(0, 0);
#endif
  for (int it = 0; it < CC / 64; ++it) {
    const int bo = it & 1;
#ifdef HAVE_GLOAD_LDS
    __syncthreads();                          // drains tile-it prefetch
    if (it + 1 < CC / 64) G1STAGE((it + 1) * 64, bo ^ 1);
#else
    __syncthreads();
    G1STAGE(it * 64, bo);
    __syncthreads();
#endif
    const int wr = (w >> 1) * 32, wc = (w & 1) * 32;
#pragma unroll
    for (int c = 0; c < 2; ++c) {
      short8 af[2], bfr[2];
#pragma unroll
      for (int i = 0; i < 2; ++i) {
        const int rowA = wr + i * 16 + lq;
        af[i] = *(const short8*)((char*)lA[bo] + rowA * 128 +
                                 ((c * 64 + lh * 16) ^ ((rowA & 7) << 4)));
        const int rowB = wc + i * 16 + lq;
        bfr[i] = *(const short8*)((char*)lB[bo] + rowB * 128 +
                                  ((c * 64 + lh * 16) ^ ((rowB & 7) << 4)));
      }
#pragma unroll
      for (int mi = 0; mi < 2; ++mi)
#pragma unroll
        for (int ni = 0; ni < 2; ++ni)
          acc[mi][ni] = __builtin_amdgcn_mfma_f32_16x16x32_bf16(
              af[mi], bfr[ni], acc[mi][ni], 0, 0, 0);
    }
  }

  const int wr = (w >> 1) * 32, wc = (w & 1) * 32;
#pragma unroll
  for (int ni = 0; ni < 2; ++ni) {
    const int fb = f0 + wc + ni * 16;
    const float bv = bias[fb + lq];
#pragma unroll
    for (int mi = 0; mi < 2; ++mi) {
      const int mb = m0 + wr + mi * 16 + 4 * lh;
#pragma unroll
      for (int r = 0; r < 4; ++r)
        Of[(size_t)(mb + r) * CC + fb + lq] = acc[mi][ni][r] + bv;
    }
  }
}

// exp + mask + pack + permlane for one q-subtile's 32-key tile.
#define EXPPACK(sacc_, pa_, l1a_, l1b_, mc_, qwoff_)                         \
  do {                                                                       \
    uint32_t dw[8];                                                          \
    if ((((qw + (qwoff_)) - kb) & 511) == 0) {                               \
      const int mreg = (((lq >> 2) & 1) == hi)                               \
                           ? ((lq & 3) | (((lq >> 3) & 3) << 2)) : -1;       \
      _Pragma("unroll")                                                      \
      for (int j2 = 0; j2 < 8; ++j2) {                                       \
        float e0 = exp2raw(sacc_[2 * j2]);                                   \
        float e1 = exp2raw(sacc_[2 * j2 + 1]);                               \
        l1a_ += e0; l1b_ += e1;                                              \
        mc_ += (2 * j2 == mreg) ? e0 : 0.f;                                  \
        mc_ += (2 * j2 + 1 == mreg) ? e1 : 0.f;                              \
        e0 = (2 * j2 == mreg) ? 0.5f * e0 : e0;                              \
        e1 = (2 * j2 + 1 == mreg) ? 0.5f * e1 : e1;                          \
        dw[j2] = cvtpk(e0, e1);                                              \
      }                                                                      \
    } else {                                                                 \
      _Pragma("unroll")                                                      \
      for (int j2 = 0; j2 < 8; ++j2) {                                       \
        const float e0 = exp2raw(sacc_[2 * j2]);                             \
        const float e1 = exp2raw(sacc_[2 * j2 + 1]);                         \
        l1a_ += e0; l1b_ += e1;                                              \
        dw[j2] = cvtpk(e0, e1);                                              \
      }                                                                      \
    }                                                                        \
    _Pragma("unroll")                                                        \
    for (int half = 0; half < 2; ++half) {                                   \
      uint32_t a0 = dw[4 * half + 0], a1 = dw[4 * half + 1];                 \
      uint32_t a2 = dw[4 * half + 2], a3 = dw[4 * half + 3];                 \
      asm("v_permlane32_swap_b32 %0, %1" : "+v"(a0), "+v"(a2));              \
      asm("v_permlane32_swap_b32 %0, %1" : "+v"(a1), "+v"(a3));              \
      union { uint32_t u4[4]; short8 s; } pk;                                \
      pk.u4[0] = a0; pk.u4[1] = a1; pk.u4[2] = a2; pk.u4[3] = a3;            \
      pa_[half] = pk.s;                                                      \
    }                                                                        \
  } while (0)

// ---------------------------------------------------------------------------
// Attention (best structure, 53.4 us): 768 blocks x 256 thr = 4 waves, each
// an independent k-chunk (512 keys) over the SAME 64 queries (2 q-subtiles
// per wave).  K DOUBLE-BUFFERED per wave (12 KB/wave); V single-buffered.
// Prefetches wrap mod 16 -> constant outstanding-count invariant.
// ZERO barriers in the K-loop.  exp2 via raw v_exp_f32.  4-way split-K
// combine via 50688 B LDS overlay (3 blocks/CU).  (256,3): (256,4)/(256,5)
// both spill (R13/R18).  Linearized 2nd softmax:
//   out = (csV*l1 + P1)/(2048*l1+s1),  s1 = l1 - 0.5*mc.
// ---------------------------------------------------------------------------
__global__ __launch_bounds__(256, 3)
void attn_k(const short* __restrict__ Qb, const short* __restrict__ Kb,
            const short* __restrict__ VT, const float* __restrict__ cs,
            short* __restrict__ AO)
{
  __shared__ __align__(16) char smem[50688];     // 4 x 12KB staging | overlay
  float* comb  = (float*)smem;                   // 3 x [64q][64d] fp32
  float* combL = (float*)(smem + 49152);         // 3 x 64 (l1 partials)
  float* combM = (float*)(smem + 49152 + 768);   // 3 x 64 (mc partials)

  const int tid = threadIdx.x;
  const int kc = tid >> 6, l = tid & 63;         // wave = k-chunk
  const int lq = l & 31, hi = l >> 5;

  // XCD-aware chunked swizzle: 768 % 8 == 0, bijective.
  const int bid = (int)blockIdx.x;
  const int sbid = (bid & 7) * 96 + (bid >> 3);
  const int bh = sbid >> 5;
  const int qsub = sbid & 31;

  const short* Qh = Qb + (size_t)bh * NN * DD;
  const short* Kh = Kb + (size_t)bh * NN * DD;
  const short* Vh = VT + (size_t)bh * DD * NN;

  const int qw = qsub * 64;

  // B-frags of Q for both subtiles: rows d = c*16 + hi*8 + 0..7, col q = lq
  short8 qf0[4], qf1[4];
#pragma unroll
  for (int c = 0; c < 4; ++c) {
    qf0[c] = *(const short8*)(Qh + (size_t)(qw + lq) * DD + c * 16 + hi * 8);
    qf1[c] = *(const short8*)(Qh + (size_t)(qw + 32 + lq) * DD + c * 16 + hi * 8);
  }

  f32x16 pv0[2] = {}, pv1[2] = {};
  float l1a0 = 0.f, l1b0 = 0.f, mc0 = 0.f;
  float l1a1 = 0.f, l1b1 = 0.f, mc1 = 0.f;

  const int cbase = kc * 12288;   // wave-private: Kbuf0 | Kbuf1 | V
  const int kb0 = kc * (NN / 4);
  const short* Kc = Kh + (size_t)kb0 * DD;
  const short* Vc = Vh + kb0;

#ifdef HAVE_GLOAD_LDS
  // staging geometry (per wave): K tile [32 k][128B], 4 x 1KB instrs;
  // V tile [64 d][64B], 4 x 1KB.  Global source pre-swizzled with the
  // frag-read XOR involution (K key: row&7; V key: VKEY(row)).
  int gK[4], gV[4];
#pragma unroll
  for (int j = 0; j < 4; ++j) {
    const int rowK = j * 8 + (l >> 3);
    gK[j] = rowK * DD + (((l & 7) ^ (l >> 3)) * 8);
    const int rowV = j * 16 + (l >> 2);
    gV[j] = rowV * NN + (((l & 3) ^ VKEY(rowV)) * 8);
  }
#define SK(t_, boff_)                                                        \
  do {                                                                       \
    _Pragma("unroll")                                                        \
    for (int j = 0; j < 4; ++j)                                              \
      GL16(Kc + (size_t)(t_) * 32 * DD + gK[j],                              \
           smem + cbase + (boff_) + j * 1024);                               \
  } while (0)
#define SV(t_)                                                               \
  do {                                                                       \
    _Pragma("unroll")                                                        \
    for (int j = 0; j < 4; ++j)                                              \
      GL16(Vc + (t_) * 32 + gV[j], smem + cbase + 8192 + j * 1024);          \
  } while (0)
#else
  // fallback: per-wave synchronous reg staging (single-buffered; lgkm-fenced)
  int sdK[4], sgK[4], sdV[4], sgV[4];
#pragma unroll
  for (int j = 0; j < 4; ++j) {
    const int rowK = j * 8 + (l >> 3);
    sdK[j] = cbase + rowK * 128 + (((l & 7) * 16) ^ ((rowK & 7) << 4));
    sgK[j] = rowK * DD + (l & 7) * 8;
    const int rowV = j * 16 + (l >> 2);
    sdV[j] = cbase + 8192 + rowV * 64 + (((l & 3) * 16) ^ (VKEY(rowV) << 4));
    sgV[j] = rowV * NN + (l & 3) * 8;
  }
#define SK(t_, boff_)                                                        \
  do {                                                                       \
    _Pragma("unroll")                                                        \
    for (int j = 0; j < 4; ++j)                                              \
      *(short8*)(smem + (boff_) + sdK[j]) =                                  \
          *(const short8*)(Kc + (size_t)(t_) * 32 * DD + sgK[j]);            \
  } while (0)
#define SV(t_)                                                               \
  do {                                                                       \
    _Pragma("unroll")                                                        \
    for (int j = 0; j < 4; ++j)                                              \
      *(short8*)(smem + sdV[j]) =                                            \
          *(const short8*)(Vc + (t_) * 32 + sgV[j]);                         \
  } while (0)
#endif

  // hoisted LDS frag-read addresses (K: add buffer offset per iter)
  int kaddr[4], vaddr[4];
#pragma unroll
  for (int c = 0; c < 4; ++c)
    kaddr[c] = cbase + lq * 128 + (((c * 2 + hi) * 16) ^ ((lq & 7) << 4));
#pragma unroll
  for (int ch = 0; ch < 2; ++ch)
#pragma unroll
    for (int dg = 0; dg < 2; ++dg) {
      const int rowV = dg * 32 + lq;
      vaddr[ch * 2 + dg] = cbase + 8192 + rowV * 64 +
                           (((ch * 2 + hi) * 16) ^ (VKEY(rowV) << 4));
    }

#ifdef HAVE_GLOAD_LDS
  SK(0, 0);
  SV(0);
  SK(1, 4096);
#else
  SK(0, 0);
  SV(0);
#endif

  for (int t = 0; t < 16; ++t) {
    const int kb = kb0 + t * 32;
#ifdef HAVE_GLOAD_LDS
    const int koff = (t & 1) * 4096;
    asm volatile("s_waitcnt vmcnt(8)" ::: "memory");   // K(t) (no-op in steady)
    __builtin_amdgcn_sched_barrier(0);
#else
    const int koff = 0;
    asm volatile("s_waitcnt lgkmcnt(0)" ::: "memory"); // ds_writes done
#endif

    // QK^T both subtiles: each K-frag read feeds 2 MFMAs.
    f32x16 sacc0 = {}, sacc1 = {};
    __builtin_amdgcn_s_setprio(1);
#pragma unroll
    for (int c = 0; c < 4; ++c) {
      short8 kf = *(const short8*)(smem + koff + kaddr[c]);
      sacc0 = __builtin_amdgcn_mfma_f32_32x32x16_bf16(kf, qf0[c], sacc0, 0, 0, 0);
      sacc1 = __builtin_amdgcn_mfma_f32_32x32x16_bf16(kf, qf1[c], sacc1, 0, 0, 0);
    }
    __builtin_amdgcn_s_setprio(0);
    asm volatile("s_waitcnt lgkmcnt(0)" ::: "memory"); // K frag reads done
    __builtin_amdgcn_sched_barrier(0);
#ifdef HAVE_GLOAD_LDS
    SK((t + 2) & 15, koff);                            // K(t+2) -> buf just freed
#endif

    // exp/pack sequentially per subtile (short dw live ranges)
    short8 pa0[2], pa1[2];
    EXPPACK(sacc0, pa0, l1a0, l1b0, mc0, 0);
    EXPPACK(sacc1, pa1, l1a1, l1b1, mc1, 32);

#ifdef HAVE_GLOAD_LDS
    asm volatile("s_waitcnt vmcnt(4)" ::: "memory");   // V(t) landed (invariant)
    __builtin_amdgcn_sched_barrier(0);
#endif

    // PV both subtiles: each V-frag read feeds 2 MFMAs.
    __builtin_amdgcn_s_setprio(1);
#pragma unroll
    for (int ch = 0; ch < 2; ++ch)
#pragma unroll
      for (int dg = 0; dg < 2; ++dg) {
        short8 vf = *(const short8*)(smem + vaddr[ch * 2 + dg]);
        pv0[dg] = __builtin_amdgcn_mfma_f32_32x32x16_bf16(pa0[ch], vf, pv0[dg], 0, 0, 0);
        pv1[dg] = __builtin_amdgcn_mfma_f32_32x32x16_bf16(pa1[ch], vf, pv1[dg], 0, 0, 0);
      }
    __builtin_amdgcn_s_setprio(0);
    asm volatile("s_waitcnt lgkmcnt(0)" ::: "memory"); // V frag reads done
    __builtin_amdgcn_sched_barrier(0);
#ifdef HAVE_GLOAD_LDS
    SV((t + 1) & 15);                                  // V(t+1) -> buf freed
#else
    if (t + 1 < 16) { SK(t + 1, 0); SV(t + 1); }
#endif
  }

  // per-chunk l1, mc per subtile (keys split across lane halves)
  float l1s[2], mcs[2];
  l1s[0] = l1a0 + l1b0;  l1s[0] += __shfl_xor(l1s[0], 32);
  l1s[1] = l1a1 + l1b1;  l1s[1] += __shfl_xor(l1s[1], 32);
  mcs[0] = mc0 + __shfl_xor(mc0, 32);
  mcs[1] = mc1 + __shfl_xor(mc1, 32);

  // ---- 4-way split-K combine via LDS overlay ----
  __syncthreads();                     // drains wrap prefetches; staging done
  if (kc) {
    float* pb = comb + (kc - 1) * 4096;
#pragma unroll
    for (int dg = 0; dg < 2; ++dg)
#pragma unroll
      for (int r = 0; r < 16; ++r) {
        const int qrow = (r & 3) + 8 * (r >> 2) + 4 * hi;
        pb[qrow * 64 + dg * 32 + lq] = pv0[dg][r];
        pb[(32 + qrow) * 64 + dg * 32 + lq] = pv1[dg][r];
      }
    if (hi == 0) {
      combL[(kc - 1) * 64 + lq]      = l1s[0];
      combL[(kc - 1) * 64 + 32 + lq] = l1s[1];
      combM[(kc - 1) * 64 + lq]      = mcs[0];
      combM[(kc - 1) * 64 + 32 + lq] = mcs[1];
    }
  }
  __syncthreads();
  if (kc == 0) {
    const int b = bh / HH, h = bh - b * HH;
#pragma unroll
    for (int s = 0; s < 2; ++s) {
      const float l1t = l1s[s] + combL[s * 32 + lq] + combL[64 + s * 32 + lq] +
                        combL[128 + s * 32 + lq];
      const float mct = mcs[s] + combM[s * 32 + lq] + combM[64 + s * 32 + lq] +
                        combM[128 + s * 32 + lq];
      const float s1t = l1t - 0.5f * mct;
#pragma unroll
      for (int r = 0; r < 16; ++r) {
        const int qrow = (r & 3) + 8 * (r >> 2) + 4 * hi;
        const float l1r = __shfl(l1t, qrow);
        const float s1r = __shfl(s1t, qrow);
        const float rden = 1.f / (2048.f * l1r + s1r);
        const int n = qw + s * 32 + qrow;
#pragma unroll
        for (int dg = 0; dg < 2; ++dg) {
          const int d = dg * 32 + lq;
          const float pvt = (s ? pv1[dg][r] : pv0[dg][r]) +
                            comb[(s * 32 + qrow) * 64 + d] +
                            comb[4096 + (s * 32 + qrow) * 64 + d] +
                            comb[8192 + (s * 32 + qrow) * 64 + d];
          const float csv = cs[bh * DD + d];
          AO[((size_t)(b * NN + n)) * CC + h * DD + d] =
              f2bf((csv * l1r + pvt) * rden);
        }
      }
    }
  }
}

// ---------------------------------------------------------------------------
extern "C" void kernel_launch(void* const* d_in, const int* in_sizes, int n_in,
                              void* d_out, int out_size, void* d_ws, size_t ws_size,
                              hipStream_t stream)
{
  (void)in_sizes; (void)n_in; (void)out_size;
  float* out = (float*)d_out;

  const size_t HD = (size_t)2 * HH * NN * DD;   // 3,145,728 elements
  const size_t NX = 3145728, NW = 1769472, NO = 589824;
  const size_t need = (4 * HD + NX + NW + NO) * sizeof(short)
                    + (size_t)2 * HH * DD * sizeof(float) + 64;
  if (ws_size < need) return;  // diagnostic: zero output

  short* Qb = (short*)d_ws;
  short* Kb = Qb + HD;
  short* VT = Kb + HD;
  short* AO = VT + HD;
  float* cs = (float*)(AO + HD);
  short* xb  = (short*)(cs + 2 * HH * DD);
  short* wqb = xb + NX;
  short* wob = wqb + NW;

  dim3 blk(256);
  norm_k<<<dim3(2688), blk, 0, stream>>>((const float*)d_in[0],
                                         (const float*)d_in[1],
                                         (const float*)d_in[2],
                                         xb, wqb, wob, cs);
  gemm0_k<<<dim3(2304 / 128, 4096 / 128), blk, 0, stream>>>(
      xb, wqb, Qb, Kb, VT, cs);
  attn_k<<<dim3(24 * 32), blk, 0, stream>>>(Qb, Kb, VT, cs, AO);
  gemm1_k<<<dim3(CC / 64, 4096 / 64), blk, 0, stream>>>(
      AO, wob, (const float*)d_in[3], out);
}

// Round 24
// 90.539 us; speedup vs baseline: 1.1052x; 1.1052x over previous
//
#include <hip/hip_runtime.h>
#include <hip/hip_bf16.h>
#include <cstdint>
#include <cstddef>

typedef __attribute__((ext_vector_type(8))) short short8;
typedef __attribute__((ext_vector_type(4))) short short4v;
typedef __attribute__((ext_vector_type(4))) float f32x4;
typedef __attribute__((ext_vector_type(16))) float f32x16;

#define HH 12
#define DD 64
#define NN 2048
#define CC 768
// 0.125 (HEAD_DIM^-0.5) * log2(e): lets attn use exp2 directly.
#define QSCALE 0.18033688011112042f

#if defined(__has_builtin)
#if __has_builtin(__builtin_amdgcn_global_load_lds)
#define HAVE_GLOAD_LDS 1
#endif
#endif

#ifdef HAVE_GLOAD_LDS
// async global->LDS, 16B per lane; LDS dest is wave-uniform base + lane*16
#define GL16(gp, lp)                                                         \
  __builtin_amdgcn_global_load_lds(                                         \
      (__attribute__((address_space(1))) void*)(size_t)(const void*)(gp),   \
      (__attribute__((address_space(3))) void*)(lp), 16, 0, 0)
#endif

__device__ __forceinline__ float bf2f(short s) {
  union { uint32_t u; float f; } v;
  v.u = ((uint32_t)(uint16_t)s) << 16;
  return v.f;
}
__device__ __forceinline__ short f2bf(float f) {
  union { float f; uint32_t u; } v; v.f = f;
  uint32_t r = v.u + 0x7FFFu + ((v.u >> 16) & 1u);
  return (short)(r >> 16);
}
// packed f32x2 -> bf16x2 (low = a, high = b) in one instruction
__device__ __forceinline__ uint32_t cvtpk(float a, float b) {
  uint32_t r;
  asm("v_cvt_pk_bf16_f32 %0, %1, %2" : "=v"(r) : "v"(a), "v"(b));
  return r;
}
// raw hardware exp2 (1 instruction; avoids hipcc's non-fast-math denorm
// fixup sequence).  Confirmed R15: VALUBusy 55->34%.
__device__ __forceinline__ float exp2raw(float x) {
  float r;
  asm("v_exp_f32 %0, %1" : "=v"(r) : "v"(x));
  return r;
}

// ---------------------------------------------------------------------------
// Normalizer: fp32 -> bf16 for x, w_qkv, w_out.  Block 0 also zeroes cs
// (colsum accumulator, filled by gemm0's V^T epilogue atomics).
// ---------------------------------------------------------------------------
__global__ __launch_bounds__(256)
void norm_k(const float* __restrict__ s0, const float* __restrict__ s1,
            const float* __restrict__ s2,
            short* __restrict__ d0, short* __restrict__ d1,
            short* __restrict__ d2, float* __restrict__ cs)
{
  const int bid = blockIdx.x;
  if (bid == 0) {
#pragma unroll
    for (int i = 0; i < 6; ++i) cs[i * 256 + threadIdx.x] = 0.f;
  }
  const float* src; short* dst; int base;
  if (bid < 1536)      { src = s0; dst = d0; base = bid; }
  else if (bid < 2400) { src = s1; dst = d1; base = bid - 1536; }
  else                 { src = s2; dst = d2; base = bid - 2400; }
  const int idx = (base * 256 + (int)threadIdx.x) * 8;
  const float* sf = src + idx;
  f32x4 a = *(const f32x4*)sf;
  f32x4 b = *(const f32x4*)(sf + 4);
  short8 o;
  o[0] = f2bf(a[0]); o[1] = f2bf(a[1]); o[2] = f2bf(a[2]); o[3] = f2bf(a[3]);
  o[4] = f2bf(b[0]); o[5] = f2bf(b[1]); o[6] = f2bf(b[2]); o[7] = f2bf(b[3]);
  *(short8*)(dst + idx) = o;
}

// ---------------------------------------------------------------------------
// QKV GEMM (128x128): C[m,f] = sum_c A[m,c] * W[f,c]
// -> Q (x QSCALE) [b,h,n,d], K [b,h,n,d], V^T [b,h,d,n].
// V^T epilogue ALSO accumulates colsum cs[bh,d] = sum_n V (fp32, wave-
// reduced over lh then one atomicAdd per lh==0 lane) -- replaces the
// standalone colsum_k dispatch (R21: -9.5 us).
// Staging: global_load_lds w16, linear LDS dest, pre-swizzled global source.
// (R23 note: async-dbuf variant of this staging REGRESSED 9 us -- barrier-
// synced dbuf drains the prefetch exposed; keep the 2-barrier sync form.)
// ---------------------------------------------------------------------------
__global__ __launch_bounds__(256, 2)
void gemm0_k(const short* __restrict__ A, const short* __restrict__ W,
             short* __restrict__ O0, short* __restrict__ O1,
             short* __restrict__ O2, float* __restrict__ cs)
{
  __shared__ __align__(16) short lA[128 * 64];
  __shared__ __align__(16) short lB[128 * 64];
  const int tid = threadIdx.x;
  const int w = tid >> 6, l = tid & 63;
  const int lq = l & 15, lh = l >> 4;
  const int m0 = blockIdx.y * 128;
  const int f0 = blockIdx.x * 128;

#ifdef HAVE_GLOAD_LDS
  const int lrow = l >> 3;                    // 0..7 within wave
  const int gseg = ((l & 7) ^ lrow) * 8;      // pre-swizzled element offset
#else
  const int seg = tid & 7;
  const int rbase = tid >> 3;
#endif

  f32x4 acc[4][4] = {};

  for (int kb = 0; kb < CC; kb += 64) {
    __syncthreads();
#ifdef HAVE_GLOAD_LDS
#pragma unroll
    for (int j = 0; j < 4; ++j) {
      const int rw = j * 32 + w * 8;          // wave-uniform row base
      const int row = rw + lrow;
      GL16(A + (size_t)(m0 + row) * CC + kb + gseg, &lA[rw * 64]);
      GL16(W + (size_t)(f0 + row) * CC + kb + gseg, &lB[rw * 64]);
    }
#else
#pragma unroll
    for (int j = 0; j < 4; ++j) {
      const int row = j * 32 + rbase;
      const int dst = row * 128 + ((seg * 16) ^ ((row & 7) << 4));
      *(short8*)((char*)lA + dst) =
          *(const short8*)(A + (size_t)(m0 + row) * CC + kb + seg * 8);
      *(short8*)((char*)lB + dst) =
          *(const short8*)(W + (size_t)(f0 + row) * CC + kb + seg * 8);
    }
#endif
    __syncthreads();
    const int wr = (w >> 1) * 64, wc = (w & 1) * 64;
#pragma unroll
    for (int c = 0; c < 2; ++c) {
      short8 af[4], bfr[4];
#pragma unroll
      for (int i = 0; i < 4; ++i) {
        const int rowA = wr + i * 16 + lq;
        af[i] = *(const short8*)((char*)lA + rowA * 128 +
                                 ((c * 64 + lh * 16) ^ ((rowA & 7) << 4)));
        const int rowB = wc + i * 16 + lq;
        bfr[i] = *(const short8*)((char*)lB + rowB * 128 +
                                  ((c * 64 + lh * 16) ^ ((rowB & 7) << 4)));
      }
#pragma unroll
      for (int mi = 0; mi < 4; ++mi)
#pragma unroll
        for (int ni = 0; ni < 4; ++ni)
          acc[mi][ni] = __builtin_amdgcn_mfma_f32_16x16x32_bf16(
              af[mi], bfr[ni], acc[mi][ni], 0, 0, 0);
    }
  }

  const int wr = (w >> 1) * 64, wc = (w & 1) * 64;
#pragma unroll
  for (int ni = 0; ni < 4; ++ni) {
    const int fb = f0 + wc + ni * 16;
    const int which = fb / CC;          // uniform per fragment
    const int hd = fb - which * CC;
    const int h = hd >> 6;              // uniform
    const int d = (hd & 63) + lq;
    if (which == 0) {
#pragma unroll
      for (int mi = 0; mi < 4; ++mi) {
        const int mb = m0 + wr + mi * 16 + 4 * lh;
        const int b = mb >> 11;
        const int n = mb & 2047;
#pragma unroll
        for (int r = 0; r < 4; ++r)
          O0[(((size_t)(b * HH + h) * NN) + n + r) * DD + d] =
              f2bf(acc[mi][ni][r] * QSCALE);
      }
    } else if (which == 1) {
#pragma unroll
      for (int mi = 0; mi < 4; ++mi) {
        const int mb = m0 + wr + mi * 16 + 4 * lh;
        const int b = mb >> 11;
        const int n = mb & 2047;
#pragma unroll
        for (int r = 0; r < 4; ++r)
          O1[(((size_t)(b * HH + h) * NN) + n + r) * DD + d] =
              f2bf(acc[mi][ni][r]);
      }
    } else {
      float csp = 0.f;                  // this thread's colsum partial
#pragma unroll
      for (int mi = 0; mi < 4; ++mi) {
        const int mb = m0 + wr + mi * 16 + 4 * lh;
        const int b = mb >> 11;
        const int n = mb & 2047;
        short4v pk;
#pragma unroll
        for (int r = 0; r < 4; ++r) {
          pk[r] = f2bf(acc[mi][ni][r]);
          csp += acc[mi][ni][r];
        }
        *(short4v*)(O2 + ((size_t)(b * HH + h) * DD + d) * NN + n) = pk;
      }
      // lanes xor 16/32 differ only in lh (same d, different n-rows)
      csp += __shfl_xor(csp, 16);
      csp += __shfl_xor(csp, 32);
      if (lh == 0) {
        const int b = (m0 + wr) >> 11;  // wave-uniform (64-row span, no straddle)
        atomicAdd(&cs[(b * HH + h) * DD + d], csp);
      }
    }
  }
}

// ---------------------------------------------------------------------------
// Out-proj GEMM, 64x64 tiles (768 blocks = 3/CU).  fp32 out + bias.
// ---------------------------------------------------------------------------
__global__ __launch_bounds__(256, 4)
void gemm1_k(const short* __restrict__ A, const short* __restrict__ W,
             const float* __restrict__ bias, float* __restrict__ Of)
{
  __shared__ __align__(16) short lA[64 * 64];
  __shared__ __align__(16) short lB[64 * 64];
  const int tid = threadIdx.x;
  const int w = tid >> 6, l = tid & 63;
  const int lq = l & 15, lh = l >> 4;
  const int m0 = blockIdx.y * 64;
  const int f0 = blockIdx.x * 64;

#ifdef HAVE_GLOAD_LDS
  const int lrow = l >> 3;
  const int gseg = ((l & 7) ^ lrow) * 8;
#else
  const int seg = tid & 7;
  const int rbase = tid >> 3;                 // 0..31
#endif

  f32x4 acc[2][2] = {};

  for (int kb = 0; kb < CC; kb += 64) {
    __syncthreads();
#ifdef HAVE_GLOAD_LDS
#pragma unroll
    for (int j = 0; j < 2; ++j) {
      const int rw = j * 32 + w * 8;
      const int row = rw + lrow;
      GL16(A + (size_t)(m0 + row) * CC + kb + gseg, &lA[rw * 64]);
      GL16(W + (size_t)(f0 + row) * CC + kb + gseg, &lB[rw * 64]);
    }
#else
#pragma unroll
    for (int j = 0; j < 2; ++j) {
      const int row = j * 32 + rbase;
      const int dst = row * 128 + ((seg * 16) ^ ((row & 7) << 4));
      *(short8*)((char*)lA + dst) =
          *(const short8*)(A + (size_t)(m0 + row) * CC + kb + seg * 8);
      *(short8*)((char*)lB + dst) =
          *(const short8*)(W + (size_t)(f0 + row) * CC + kb + seg * 8);
    }
#endif
    __syncthreads();
    const int wr = (w >> 1) * 32, wc = (w & 1) * 32;
#pragma unroll
    for (int c = 0; c < 2; ++c) {
      short8 af[2], bfr[2];
#pragma unroll
      for (int i = 0; i < 2; ++i) {
        const int rowA = wr + i * 16 + lq;
        af[i] = *(const short8*)((char*)lA + rowA * 128 +
                                 ((c * 64 + lh * 16) ^ ((rowA & 7) << 4)));
        const int rowB = wc + i * 16 + lq;
        bfr[i] = *(const short8*)((char*)lB + rowB * 128 +
                                  ((c * 64 + lh * 16) ^ ((rowB & 7) << 4)));
      }
#pragma unroll
      for (int mi = 0; mi < 2; ++mi)
#pragma unroll
        for (int ni = 0; ni < 2; ++ni)
          acc[mi][ni] = __builtin_amdgcn_mfma_f32_16x16x32_bf16(
              af[mi], bfr[ni], acc[mi][ni], 0, 0, 0);
    }
  }

  const int wr = (w >> 1) * 32, wc = (w & 1) * 32;
#pragma unroll
  for (int ni = 0; ni < 2; ++ni) {
    const int fb = f0 + wc + ni * 16;
    const float bv = bias[fb + lq];
#pragma unroll
    for (int mi = 0; mi < 2; ++mi) {
      const int mb = m0 + wr + mi * 16 + 4 * lh;
#pragma unroll
      for (int r = 0; r < 4; ++r)
        Of[(size_t)(mb + r) * CC + fb + lq] = acc[mi][ni][r] + bv;
    }
  }
}

// exp + mask + pack + permlane for one q-subtile's 32-key tile.
#define EXPPACK(sacc_, pa_, l1a_, l1b_, mc_, qwoff_)                         \
  do {                                                                       \
    uint32_t dw[8];                                                          \
    if ((((qw + (qwoff_)) - kb) & 511) == 0) {                               \
      const int mreg = (((lq >> 2) & 1) == hi)                               \
                           ? ((lq & 3) | (((lq >> 3) & 3) << 2)) : -1;       \
      _Pragma("unroll")                                                      \
      for (int j2 = 0; j2 < 8; ++j2) {                                       \
        float e0 = exp2raw(sacc_[2 * j2]);                                   \
        float e1 = exp2raw(sacc_[2 * j2 + 1]);                               \
        l1a_ += e0; l1b_ += e1;                                              \
        mc_ += (2 * j2 == mreg) ? e0 : 0.f;                                  \
        mc_ += (2 * j2 + 1 == mreg) ? e1 : 0.f;                              \
        e0 = (2 * j2 == mreg) ? 0.5f * e0 : e0;                              \
        e1 = (2 * j2 + 1 == mreg) ? 0.5f * e1 : e1;                          \
        dw[j2] = cvtpk(e0, e1);                                              \
      }                                                                      \
    } else {                                                                 \
      _Pragma("unroll")                                                      \
      for (int j2 = 0; j2 < 8; ++j2) {                                       \
        const float e0 = exp2raw(sacc_[2 * j2]);                             \
        const float e1 = exp2raw(sacc_[2 * j2 + 1]);                         \
        l1a_ += e0; l1b_ += e1;                                              \
        dw[j2] = cvtpk(e0, e1);                                              \
      }                                                                      \
    }                                                                        \
    _Pragma("unroll")                                                        \
    for (int half = 0; half < 2; ++half) {                                   \
      uint32_t a0 = dw[4 * half + 0], a1 = dw[4 * half + 1];                 \
      uint32_t a2 = dw[4 * half + 2], a3 = dw[4 * half + 3];                 \
      asm("v_permlane32_swap_b32 %0, %1" : "+v"(a0), "+v"(a2));              \
      asm("v_permlane32_swap_b32 %0, %1" : "+v"(a1), "+v"(a3));              \
      union { uint32_t u4[4]; short8 s; } pk;                                \
      pk.u4[0] = a0; pk.u4[1] = a1; pk.u4[2] = a2; pk.u4[3] = a3;            \
      pa_[half] = pk.s;                                                      \
    }                                                                        \
  } while (0)

// ---------------------------------------------------------------------------
// Attention (best structure, 53.4 us): 768 blocks x 256 thr = 4 waves, each
// an independent k-chunk (512 keys) over the SAME 64 queries (2 q-subtiles
// per wave).  K DOUBLE-BUFFERED per wave (12 KB/wave); V single-buffered.
// Prefetches wrap mod 16 -> constant outstanding-count invariant.
// ZERO barriers in the K-loop.  exp2 via raw v_exp_f32.  4-way split-K
// combine via 50688 B LDS overlay (3 blocks/CU).  (256,3): (256,4)/(256,5)
// both spill (R13/R18).  Linearized 2nd softmax:
//   out = (csV*l1 + P1)/(2048*l1+s1),  s1 = l1 - 0.5*mc.
// ---------------------------------------------------------------------------
__global__ __launch_bounds__(256, 3)
void attn_k(const short* __restrict__ Qb, const short* __restrict__ Kb,
            const short* __restrict__ VT, const float* __restrict__ cs,
            short* __restrict__ AO)
{
  __shared__ __align__(16) char smem[50688];     // 4 x 12KB staging | overlay
  float* comb  = (float*)smem;                   // 3 x [64q][64d] fp32
  float* combL = (float*)(smem + 49152);         // 3 x 64 (l1 partials)
  float* combM = (float*)(smem + 49152 + 768);   // 3 x 64 (mc partials)

  const int tid = threadIdx.x;
  const int kc = tid >> 6, l = tid & 63;         // wave = k-chunk
  const int lq = l & 31, hi = l >> 5;

  // XCD-aware chunked swizzle: 768 % 8 == 0, bijective.
  const int bid = (int)blockIdx.x;
  const int sbid = (bid & 7) * 96 + (bid >> 3);
  const int bh = sbid >> 5;
  const int qsub = sbid & 31;

  const short* Qh = Qb + (size_t)bh * NN * DD;
  const short* Kh = Kb + (size_t)bh * NN * DD;
  const short* Vh = VT + (size_t)bh * DD * NN;

  const int qw = qsub * 64;

  // B-frags of Q for both subtiles: rows d = c*16 + hi*8 + 0..7, col q = lq
  short8 qf0[4], qf1[4];
#pragma unroll
  for (int c = 0; c < 4; ++c) {
    qf0[c] = *(const short8*)(Qh + (size_t)(qw + lq) * DD + c * 16 + hi * 8);
    qf1[c] = *(const short8*)(Qh + (size_t)(qw + 32 + lq) * DD + c * 16 + hi * 8);
  }

  f32x16 pv0[2] = {}, pv1[2] = {};
  float l1a0 = 0.f, l1b0 = 0.f, mc0 = 0.f;
  float l1a1 = 0.f, l1b1 = 0.f, mc1 = 0.f;

  const int cbase = kc * 12288;   // wave-private: Kbuf0 | Kbuf1 | V
  const int kb0 = kc * (NN / 4);
  const short* Kc = Kh + (size_t)kb0 * DD;
  const short* Vc = Vh + kb0;

#ifdef HAVE_GLOAD_LDS
  // staging geometry (per wave): K tile [32 k][128B], 4 x 1KB instrs;
  // V tile [64 d][64B], 4 x 1KB.  Global source pre-swizzled with the
  // frag-read XOR involution (K key: row&7; V key: (row>>1)&3).
  int gK[4], gV[4];
#pragma unroll
  for (int j = 0; j < 4; ++j) {
    const int rowK = j * 8 + (l >> 3);
    gK[j] = rowK * DD + (((l & 7) ^ (l >> 3)) * 8);
    const int rowV = j * 16 + (l >> 2);
    gV[j] = rowV * NN + (((l & 3) ^ ((rowV >> 1) & 3)) * 8);
  }
#define SK(t_, boff_)                                                        \
  do {                                                                       \
    _Pragma("unroll")                                                        \
    for (int j = 0; j < 4; ++j)                                              \
      GL16(Kc + (size_t)(t_) * 32 * DD + gK[j],                              \
           smem + cbase + (boff_) + j * 1024);                               \
  } while (0)
#define SV(t_)                                                               \
  do {                                                                       \
    _Pragma("unroll")                                                        \
    for (int j = 0; j < 4; ++j)                                              \
      GL16(Vc + (t_) * 32 + gV[j], smem + cbase + 8192 + j * 1024);          \
  } while (0)
#else
  // fallback: per-wave synchronous reg staging (single-buffered; lgkm-fenced)
  int sdK[4], sgK[4], sdV[4], sgV[4];
#pragma unroll
  for (int j = 0; j < 4; ++j) {
    const int rowK = j * 8 + (l >> 3);
    sdK[j] = cbase + rowK * 128 + (((l & 7) * 16) ^ ((rowK & 7) << 4));
    sgK[j] = rowK * DD + (l & 7) * 8;
    const int rowV = j * 16 + (l >> 2);
    sdV[j] = cbase + 8192 + rowV * 64 + (((l & 3) * 16) ^ (((rowV >> 1) & 3) << 4));
    sgV[j] = rowV * NN + (l & 3) * 8;
  }
#define SK(t_, boff_)                                                        \
  do {                                                                       \
    _Pragma("unroll")                                                        \
    for (int j = 0; j < 4; ++j)                                              \
      *(short8*)(smem + (boff_) + sdK[j]) =                                  \
          *(const short8*)(Kc + (size_t)(t_) * 32 * DD + sgK[j]);            \
  } while (0)
#define SV(t_)                                                               \
  do {                                                                       \
    _Pragma("unroll")                                                        \
    for (int j = 0; j < 4; ++j)                                              \
      *(short8*)(smem + sdV[j]) =                                            \
          *(const short8*)(Vc + (t_) * 32 + sgV[j]);                         \
  } while (0)
#endif

  // hoisted LDS frag-read addresses (K: add buffer offset per iter)
  int kaddr[4], vaddr[4];
#pragma unroll
  for (int c = 0; c < 4; ++c)
    kaddr[c] = cbase + lq * 128 + (((c * 2 + hi) * 16) ^ ((lq & 7) << 4));
#pragma unroll
  for (int ch = 0; ch < 2; ++ch)
#pragma unroll
    for (int dg = 0; dg < 2; ++dg) {
      const int rowV = dg * 32 + lq;
      vaddr[ch * 2 + dg] = cbase + 8192 + rowV * 64 +
                           (((ch * 2 + hi) * 16) ^ (((rowV >> 1) & 3) << 4));
    }

#ifdef HAVE_GLOAD_LDS
  SK(0, 0);
  SV(0);
  SK(1, 4096);
#else
  SK(0, 0);
  SV(0);
#endif

  for (int t = 0; t < 16; ++t) {
    const int kb = kb0 + t * 32;
#ifdef HAVE_GLOAD_LDS
    const int koff = (t & 1) * 4096;
    asm volatile("s_waitcnt vmcnt(8)" ::: "memory");   // K(t) (no-op in steady)
    __builtin_amdgcn_sched_barrier(0);
#else
    const int koff = 0;
    asm volatile("s_waitcnt lgkmcnt(0)" ::: "memory"); // ds_writes done
#endif

    // QK^T both subtiles: each K-frag read feeds 2 MFMAs.
    f32x16 sacc0 = {}, sacc1 = {};
    __builtin_amdgcn_s_setprio(1);
#pragma unroll
    for (int c = 0; c < 4; ++c) {
      short8 kf = *(const short8*)(smem + koff + kaddr[c]);
      sacc0 = __builtin_amdgcn_mfma_f32_32x32x16_bf16(kf, qf0[c], sacc0, 0, 0, 0);
      sacc1 = __builtin_amdgcn_mfma_f32_32x32x16_bf16(kf, qf1[c], sacc1, 0, 0, 0);
    }
    __builtin_amdgcn_s_setprio(0);
    asm volatile("s_waitcnt lgkmcnt(0)" ::: "memory"); // K frag reads done
    __builtin_amdgcn_sched_barrier(0);
#ifdef HAVE_GLOAD_LDS
    SK((t + 2) & 15, koff);                            // K(t+2) -> buf just freed
#endif

    // exp/pack sequentially per subtile (short dw live ranges)
    short8 pa0[2], pa1[2];
    EXPPACK(sacc0, pa0, l1a0, l1b0, mc0, 0);
    EXPPACK(sacc1, pa1, l1a1, l1b1, mc1, 32);

#ifdef HAVE_GLOAD_LDS
    asm volatile("s_waitcnt vmcnt(4)" ::: "memory");   // V(t) landed (invariant)
    __builtin_amdgcn_sched_barrier(0);
#endif

    // PV both subtiles: each V-frag read feeds 2 MFMAs.
    __builtin_amdgcn_s_setprio(1);
#pragma unroll
    for (int ch = 0; ch < 2; ++ch)
#pragma unroll
      for (int dg = 0; dg < 2; ++dg) {
        short8 vf = *(const short8*)(smem + vaddr[ch * 2 + dg]);
        pv0[dg] = __builtin_amdgcn_mfma_f32_32x32x16_bf16(pa0[ch], vf, pv0[dg], 0, 0, 0);
        pv1[dg] = __builtin_amdgcn_mfma_f32_32x32x16_bf16(pa1[ch], vf, pv1[dg], 0, 0, 0);
      }
    __builtin_amdgcn_s_setprio(0);
    asm volatile("s_waitcnt lgkmcnt(0)" ::: "memory"); // V frag reads done
    __builtin_amdgcn_sched_barrier(0);
#ifdef HAVE_GLOAD_LDS
    SV((t + 1) & 15);                                  // V(t+1) -> buf freed
#else
    if (t + 1 < 16) { SK(t + 1, 0); SV(t + 1); }
#endif
  }

  // per-chunk l1, mc per subtile (keys split across lane halves)
  float l1s[2], mcs[2];
  l1s[0] = l1a0 + l1b0;  l1s[0] += __shfl_xor(l1s[0], 32);
  l1s[1] = l1a1 + l1b1;  l1s[1] += __shfl_xor(l1s[1], 32);
  mcs[0] = mc0 + __shfl_xor(mc0, 32);
  mcs[1] = mc1 + __shfl_xor(mc1, 32);

  // ---- 4-way split-K combine via LDS overlay ----
  __syncthreads();                     // drains wrap prefetches; staging done
  if (kc) {
    float* pb = comb + (kc - 1) * 4096;
#pragma unroll
    for (int dg = 0; dg < 2; ++dg)
#pragma unroll
      for (int r = 0; r < 16; ++r) {
        const int qrow = (r & 3) + 8 * (r >> 2) + 4 * hi;
        pb[qrow * 64 + dg * 32 + lq] = pv0[dg][r];
        pb[(32 + qrow) * 64 + dg * 32 + lq] = pv1[dg][r];
      }
    if (hi == 0) {
      combL[(kc - 1) * 64 + lq]      = l1s[0];
      combL[(kc - 1) * 64 + 32 + lq] = l1s[1];
      combM[(kc - 1) * 64 + lq]      = mcs[0];
      combM[(kc - 1) * 64 + 32 + lq] = mcs[1];
    }
  }
  __syncthreads();
  if (kc == 0) {
    const int b = bh / HH, h = bh - b * HH;
#pragma unroll
    for (int s = 0; s < 2; ++s) {
      const float l1t = l1s[s] + combL[s * 32 + lq] + combL[64 + s * 32 + lq] +
                        combL[128 + s * 32 + lq];
      const float mct = mcs[s] + combM[s * 32 + lq] + combM[64 + s * 32 + lq] +
                        combM[128 + s * 32 + lq];
      const float s1t = l1t - 0.5f * mct;
#pragma unroll
      for (int r = 0; r < 16; ++r) {
        const int qrow = (r & 3) + 8 * (r >> 2) + 4 * hi;
        const float l1r = __shfl(l1t, qrow);
        const float s1r = __shfl(s1t, qrow);
        const float rden = 1.f / (2048.f * l1r + s1r);
        const int n = qw + s * 32 + qrow;
#pragma unroll
        for (int dg = 0; dg < 2; ++dg) {
          const int d = dg * 32 + lq;
          const float pvt = (s ? pv1[dg][r] : pv0[dg][r]) +
                            comb[(s * 32 + qrow) * 64 + d] +
                            comb[4096 + (s * 32 + qrow) * 64 + d] +
                            comb[8192 + (s * 32 + qrow) * 64 + d];
          const float csv = cs[bh * DD + d];
          AO[((size_t)(b * NN + n)) * CC + h * DD + d] =
              f2bf((csv * l1r + pvt) * rden);
        }
      }
    }
  }
}

// ---------------------------------------------------------------------------
extern "C" void kernel_launch(void* const* d_in, const int* in_sizes, int n_in,
                              void* d_out, int out_size, void* d_ws, size_t ws_size,
                              hipStream_t stream)
{
  (void)in_sizes; (void)n_in; (void)out_size;
  float* out = (float*)d_out;

  const size_t HD = (size_t)2 * HH * NN * DD;   // 3,145,728 elements
  const size_t NX = 3145728, NW = 1769472, NO = 589824;
  const size_t need = (4 * HD + NX + NW + NO) * sizeof(short)
                    + (size_t)2 * HH * DD * sizeof(float) + 64;
  if (ws_size < need) return;  // diagnostic: zero output

  short* Qb = (short*)d_ws;
  short* Kb = Qb + HD;
  short* VT = Kb + HD;
  short* AO = VT + HD;
  float* cs = (float*)(AO + HD);
  short* xb  = (short*)(cs + 2 * HH * DD);
  short* wqb = xb + NX;
  short* wob = wqb + NW;

  dim3 blk(256);
  norm_k<<<dim3(2688), blk, 0, stream>>>((const float*)d_in[0],
                                         (const float*)d_in[1],
                                         (const float*)d_in[2],
                                         xb, wqb, wob, cs);
  gemm0_k<<<dim3(2304 / 128, 4096 / 128), blk, 0, stream>>>(
      xb, wqb, Qb, Kb, VT, cs);
  attn_k<<<dim3(24 * 32), blk, 0, stream>>>(Qb, Kb, VT, cs, AO);
  gemm1_k<<<dim3(CC / 64, 4096 / 64), blk, 0, stream>>>(
      AO, wob, (const float*)d_in[3], out);
}